// Round 5
// baseline (305.778 us; speedup 1.0000x reference)
//
#include <hip/hip_runtime.h>
#include <hip/hip_bf16.h>

#define B 32
#define S 2048
#define E 1024
#define H 1024
#define MASK_VAL -50000.0f

typedef __attribute__((ext_vector_type(8))) short bf16x8_t;
typedef __attribute__((ext_vector_type(4))) float f32x4_t;

__device__ __forceinline__ float fast_tanh(float x) {
    float a = fabsf(x);
    float e = __expf(-2.0f * a);
    float t = (1.0f - e) / (1.0f + e);
    return copysignf(t, x);
}

__device__ __forceinline__ float b2f(short s) {
    return __uint_as_float(((unsigned)(unsigned short)s) << 16);
}

__device__ __forceinline__ bf16x8_t cvt8(const float4 f0, const float4 f1) {
    union { bf16x8_t s8; __hip_bfloat162 h[4]; } u;
    u.h[0] = __float22bfloat162_rn(make_float2(f0.x, f0.y));
    u.h[1] = __float22bfloat162_rn(make_float2(f0.z, f0.w));
    u.h[2] = __float22bfloat162_rn(make_float2(f1.x, f1.y));
    u.h[3] = __float22bfloat162_rn(make_float2(f1.z, f1.w));
    return u.s8;
}

__device__ __forceinline__ void gload16(const void* g, void* l) {
    __builtin_amdgcn_global_load_lds(
        (const __attribute__((address_space(1))) void*)g,
        (__attribute__((address_space(3))) void*)l, 16, 0, 0);
}

// kprep: [0,1024) W->bf16; [1024,1152) dec_proj; [1152,1664) enc->bf16 (active)
__global__ __launch_bounds__(256) void kprep(
    const float* __restrict__ W, const float* __restrict__ dec,
    const float* __restrict__ enc, const int* __restrict__ seq,
    __hip_bfloat16* __restrict__ Wb, float* __restrict__ dec_proj,
    __hip_bfloat16* __restrict__ encb)
{
    int blk = blockIdx.x, tid = threadIdx.x;
    if (blk < 1024) {
        int idx = (blk * 256 + tid) * 4;   // over H*E
        int h = idx >> 10, e = idx & 1023;
        float4 f = *(const float4*)(W + (size_t)h * 2048 + e);
        __hip_bfloat162 p0 = __float22bfloat162_rn(make_float2(f.x, f.y));
        __hip_bfloat162 p1 = __float22bfloat162_rn(make_float2(f.z, f.w));
        *reinterpret_cast<__hip_bfloat162*>(Wb + idx)     = p0;
        *reinterpret_cast<__hip_bfloat162*>(Wb + idx + 2) = p1;
    } else if (blk < 1152) {
        int gid = (blk - 1024) * 256 + tid;   // 32768 total
        int b = gid >> 10, h = gid & 1023;
        const float4* wd = (const float4*)(W + (size_t)h * 2048 + 1024);
        const float4* dd = (const float4*)(dec + b * 1024);
        float acc = 0.f;
        for (int d = 0; d < 256; ++d) {
            float4 w4 = wd[d], d4 = dd[d];
            acc += w4.x * d4.x + w4.y * d4.y + w4.z * d4.z + w4.w * d4.w;
        }
        dec_proj[gid] = acc;
    } else {
        int g = blk - 1152;           // 512 blocks: 16 s-chunks x 32 b
        int c = g & 15, b = g >> 4;
        if (c * 128 >= seq[b]) return;
        size_t base = ((size_t)b * S + c * 128) * E;
        const float* src = enc + base;
        __hip_bfloat16* dst = encb + base;
        #pragma unroll 4
        for (int it = 0; it < 64; ++it) {
            int idx = it * 2048 + tid * 8;
            float4 f0 = *(const float4*)(src + idx);
            float4 f1 = *(const float4*)(src + idx + 4);
            *(bf16x8_t*)(dst + idx) = cvt8(f0, f1);
        }
    }
}

// K2: 256x256 tile (s x h), BK=64, K=1024, 8 waves (2M x 4N), per-wave 128x64.
// 2-phase double-buffer: stage(next) issued before ds_read+MFMA(cur); single
// barrier per K-step drains vmcnt. LDS XOR-swizzle (row&7)<<4 via pre-swizzled
// global source (linear gload_lds dest) + swizzled ds_read.
// Grid 1024: bid -> xcd=bid&7; q=bid>>3; nt=q&3; p=(q>>2)*8+xcd; b=p>>3; st=p&7
// so the 4 nt-blocks of one (b,st) share an XCD (A-tile L2 reuse).
template<int AMODE>
__global__ __launch_bounds__(512, 2) void k2_mfma(
    const float* __restrict__ enc, const __hip_bfloat16* __restrict__ encb,
    const __hip_bfloat16* __restrict__ Wb, const float* __restrict__ v,
    const float* __restrict__ dec_proj, const int* __restrict__ seq,
    float* __restrict__ part)
{
    const int bid = blockIdx.x;
    const int xcd = bid & 7;
    const int q   = bid >> 3;
    const int nt  = q & 3;
    const int p   = (q >> 2) * 8 + xcd;
    const int b   = p >> 3;
    const int st  = p & 7;
    const int s0  = st * 256;
    if (s0 >= seq[b]) return;
    const int h0 = nt * 256;

    const int tid  = threadIdx.x;
    const int wave = tid >> 6;
    const int lane = tid & 63;
    const int wr = wave >> 2, wc = wave & 3;   // 2 x 4 wave grid
    const int cr = lane & 15, cg = lane >> 4;

    __shared__ __hip_bfloat16 Al[2][256 * 64];
    __shared__ __hip_bfloat16 Bl[2][256 * 64];

    const int colb  = (tid & 7) * 16;   // byte col within 128B LDS row
    const int rbase = tid >> 3;         // 0..63

    f32x4_t acc[8][4];
    #pragma unroll
    for (int m = 0; m < 8; ++m)
        #pragma unroll
        for (int n = 0; n < 4; ++n)
            acc[m][n] = (f32x4_t){0.f, 0.f, 0.f, 0.f};

    auto stage = [&](int buf, int kt) {
        #pragma unroll
        for (int i = 0; i < 4; ++i) {
            const int row   = i * 64 + rbase;
            const int scolb = colb ^ ((row & 7) << 4);
            const __hip_bfloat16* bg =
                Wb + (((size_t)(h0 + row)) << 10) + kt * 64 + (scolb >> 1);
            gload16(bg, (char*)&Bl[buf][0] + (i * 512 + tid) * 16);
            if (AMODE == 0) {
                const __hip_bfloat16* ag =
                    encb + (((size_t)b * S + s0 + row) << 10) + kt * 64 + (scolb >> 1);
                gload16(ag, (char*)&Al[buf][0] + (i * 512 + tid) * 16);
            } else {
                const float* af =
                    enc + (((size_t)b * S + s0 + row) << 10) + kt * 64 + (tid & 7) * 8;
                bf16x8_t v8 = cvt8(*(const float4*)af, *(const float4*)(af + 4));
                *(bf16x8_t*)((char*)&Al[buf][0] + row * 128 + scolb) = v8;
            }
        }
    };

    stage(0, 0);
    __syncthreads();
    int cur = 0;
    for (int kt = 0; kt < 16; ++kt) {
        if (kt < 15) stage(cur ^ 1, kt + 1);   // flies under the MFMAs below
        #pragma unroll
        for (int ks = 0; ks < 2; ++ks) {
            bf16x8_t afr[8], bfr[4];
            #pragma unroll
            for (int m = 0; m < 8; ++m) {
                const int arow  = wr * 128 + m * 16 + cr;
                const int acolb = (ks * 64 + cg * 16) ^ ((arow & 7) << 4);
                afr[m] = *(const bf16x8_t*)((const char*)&Al[cur][0] + arow * 128 + acolb);
            }
            #pragma unroll
            for (int n = 0; n < 4; ++n) {
                const int brow  = wc * 64 + n * 16 + cr;
                const int bcolb = (ks * 64 + cg * 16) ^ ((brow & 7) << 4);
                bfr[n] = *(const bf16x8_t*)((const char*)&Bl[cur][0] + brow * 128 + bcolb);
            }
            #pragma unroll
            for (int m = 0; m < 8; ++m)
                #pragma unroll
                for (int n = 0; n < 4; ++n)
                    acc[m][n] = __builtin_amdgcn_mfma_f32_16x16x32_bf16(
                        afr[m], bfr[n], acc[m][n], 0, 0, 0);
        }
        __syncthreads();   // drains vmcnt: next buf ready, cur consumed
        cur ^= 1;
    }

    // Epilogue: t = v*tanh(acc + dec_proj); reduce over n frags + 16 cr lanes.
    float vv[4], dp[4];
    #pragma unroll
    for (int n = 0; n < 4; ++n) {
        int h = h0 + wc * 64 + n * 16 + cr;
        vv[n] = v[h];
        dp[n] = dec_proj[b * H + h];
    }
    #pragma unroll
    for (int m = 0; m < 8; ++m) {
        #pragma unroll
        for (int j = 0; j < 4; ++j) {
            float t = 0.f;
            #pragma unroll
            for (int n = 0; n < 4; ++n)
                t += vv[n] * fast_tanh(acc[m][n][j] + dp[n]);
            t += __shfl_xor(t, 1);
            t += __shfl_xor(t, 2);
            t += __shfl_xor(t, 4);
            t += __shfl_xor(t, 8);
            if (cr == 0) {
                int srow = s0 + wr * 128 + m * 16 + cg * 4 + j;
                part[(size_t)(b * S + srow) * 16 + nt * 4 + wc] = t;
            }
        }
    }
}

// K3: sum 16 partials -> logit; masked softmax over s per batch
__global__ __launch_bounds__(256) void k3_softmax(
    const float* __restrict__ part, const int* __restrict__ seq,
    float* __restrict__ attn)
{
    int b = blockIdx.x, tid = threadIdx.x;
    int len = seq[b];
    float vals[8];
    float mx = -3.4e38f;
    #pragma unroll
    for (int i = 0; i < 8; ++i) {
        int s = i * 256 + tid;
        float x = MASK_VAL;
        if (s < len) {
            const f32x4_t* p = (const f32x4_t*)&part[(size_t)(b * S + s) * 16];
            f32x4_t a = p[0], c = p[1], d = p[2], e = p[3];
            x = (a[0] + a[1] + a[2] + a[3]) + (c[0] + c[1] + c[2] + c[3]) +
                (d[0] + d[1] + d[2] + d[3]) + (e[0] + e[1] + e[2] + e[3]);
        }
        vals[i] = x;
        mx = fmaxf(mx, x);
    }
    #pragma unroll
    for (int off = 1; off < 64; off <<= 1) mx = fmaxf(mx, __shfl_xor(mx, off));
    __shared__ float red[8];
    int wave = tid >> 6, lane = tid & 63;
    if (lane == 0) red[wave] = mx;
    __syncthreads();
    mx = fmaxf(fmaxf(red[0], red[1]), fmaxf(red[2], red[3]));
    float e[8];
    float sum = 0.f;
    #pragma unroll
    for (int i = 0; i < 8; ++i) { e[i] = __expf(vals[i] - mx); sum += e[i]; }
    #pragma unroll
    for (int off = 1; off < 64; off <<= 1) sum += __shfl_xor(sum, off);
    if (lane == 0) red[4 + wave] = sum;
    __syncthreads();
    sum = red[4] + red[5] + red[6] + red[7];
    float inv = 1.0f / sum;
    #pragma unroll
    for (int i = 0; i < 8; ++i) attn[b * S + i * 256 + tid] = e[i] * inv;
}

// K4: opart partial weighted sums. AMODE 0: bf16 encb; AMODE 1: fp32 enc.
template<int AMODE>
__global__ __launch_bounds__(256) void k4_partial(
    const float* __restrict__ enc, const __hip_bfloat16* __restrict__ encb,
    const float* __restrict__ attn, const int* __restrict__ seq,
    float* __restrict__ opart)
{
    int c = blockIdx.x, b = blockIdx.y, tid = threadIdx.x;
    int base_s = c * 256;
    int len = seq[b];
    if (AMODE == 0) {
        int e0 = (tid & 127) * 8;
        int so = tid >> 7;
        float av[8];
        #pragma unroll
        for (int j = 0; j < 8; ++j) av[j] = 0.f;
        if (base_s < len) {
            int s_end = min(256, len - base_s);
            for (int s = so; s < s_end; s += 2) {
                float w = attn[b * S + base_s + s];
                bf16x8_t u = *(const bf16x8_t*)(encb +
                    (((size_t)b * S + base_s + s) << 10) + e0);
                #pragma unroll
                for (int j = 0; j < 8; ++j) av[j] += w * b2f(u[j]);
            }
        }
        float* dst = opart + (((size_t)(b * 8 + c) * 2 + so) << 10) + e0;
        *(float4*)dst       = make_float4(av[0], av[1], av[2], av[3]);
        *(float4*)(dst + 4) = make_float4(av[4], av[5], av[6], av[7]);
    } else {
        float4 acc = make_float4(0.f, 0.f, 0.f, 0.f);
        if (base_s < len) {
            int s_end = min(256, len - base_s);
            const float* ep = enc + ((size_t)b * S + base_s) * E + (tid & 255) * 4;
            const float* ap = attn + b * S + base_s;
            for (int s = 0; s < s_end; ++s) {
                float w = ap[s];
                float4 ev = *(const float4*)ep;
                ep += E;
                acc.x += w * ev.x; acc.y += w * ev.y;
                acc.z += w * ev.z; acc.w += w * ev.w;
            }
        }
        float* dst = opart + (((size_t)(b * 8 + c) * 2) << 10) + tid * 4;
        *(float4*)dst = acc;
        float* dst2 = opart + (((size_t)(b * 8 + c) * 2 + 1) << 10) + tid * 4;
        *(float4*)dst2 = make_float4(0.f, 0.f, 0.f, 0.f);
    }
}

// K5: out[b][e] = sum over 16 partials
__global__ __launch_bounds__(256) void k5_reduce(
    const float* __restrict__ opart, float* __restrict__ out)
{
    int gid = blockIdx.x * 256 + threadIdx.x;  // 32768 = B*E
    int b = gid >> 10, e = gid & 1023;
    float s = 0.f;
    #pragma unroll
    for (int c = 0; c < 16; ++c) s += opart[((size_t)(b * 16 + c) << 10) + e];
    out[gid] = s;
}

extern "C" void kernel_launch(void* const* d_in, const int* in_sizes, int n_in,
                              void* d_out, int out_size, void* d_ws, size_t ws_size,
                              hipStream_t stream)
{
    const float* enc = (const float*)d_in[0];
    const int*   seq = (const int*)d_in[1];
    const float* dec = (const float*)d_in[2];
    const float* W   = (const float*)d_in[3];
    const float* v   = (const float*)d_in[4];

    float* out  = (float*)d_out;            // (B, E)
    float* attn = out + B * E;              // (B, S)

    float* dec_proj = (float*)d_ws;                         // B*H
    float* part     = dec_proj + B * H;                     // B*S*16
    float* opart    = part + (size_t)B * S * 16;            // B*16*1024
    __hip_bfloat16* Wb = (__hip_bfloat16*)(opart + (size_t)B * 16 * 1024);
    __hip_bfloat16* encb = Wb + (size_t)H * E;              // B*S*E bf16

    const size_t need = (size_t)(B * H + B * S * 16 + B * 16 * 1024) * 4
                      + (size_t)H * E * 2 + (size_t)B * S * E * 2;
    const bool use_encb = ws_size >= need;

    if (use_encb) {
        hipLaunchKernelGGL(kprep, dim3(1664), dim3(256), 0, stream,
                           W, dec, enc, seq, Wb, dec_proj, encb);
        hipLaunchKernelGGL(k2_mfma<0>, dim3(1024), dim3(512), 0, stream,
                           enc, encb, Wb, v, dec_proj, seq, part);
    } else {
        hipLaunchKernelGGL(kprep, dim3(1152), dim3(256), 0, stream,
                           W, dec, enc, seq, Wb, dec_proj, encb);
        hipLaunchKernelGGL(k2_mfma<1>, dim3(1024), dim3(512), 0, stream,
                           enc, encb, Wb, v, dec_proj, seq, part);
    }
    hipLaunchKernelGGL(k3_softmax, dim3(B), dim3(256), 0, stream,
                       part, seq, attn);
    if (use_encb) {
        hipLaunchKernelGGL(k4_partial<0>, dim3(8, B), dim3(256), 0, stream,
                           enc, encb, attn, seq, opart);
    } else {
        hipLaunchKernelGGL(k4_partial<1>, dim3(8, B), dim3(256), 0, stream,
                           enc, encb, attn, seq, opart);
    }
    hipLaunchKernelGGL(k5_reduce, dim3(B * E / 256), dim3(256), 0, stream,
                       opart, out);
}

// Round 8
// 302.885 us; speedup vs baseline: 1.0096x; 1.0096x over previous
//
#include <hip/hip_runtime.h>
#include <hip/hip_bf16.h>

#define B 32
#define S 2048
#define E 1024
#define H 1024
#define MASK_VAL -50000.0f

typedef __attribute__((ext_vector_type(8))) short bf16x8_t;
typedef __attribute__((ext_vector_type(4))) float f32x4_t;

__device__ __forceinline__ float fast_tanh(float x) {
    float a = fabsf(x);
    float e = __expf(-2.0f * a);
    float t = (1.0f - e) / (1.0f + e);
    return copysignf(t, x);
}

__device__ __forceinline__ float b2f(short s) {
    return __uint_as_float(((unsigned)(unsigned short)s) << 16);
}

__device__ __forceinline__ bf16x8_t cvt8(const float4 f0, const float4 f1) {
    union { bf16x8_t s8; __hip_bfloat162 h[4]; } u;
    u.h[0] = __float22bfloat162_rn(make_float2(f0.x, f0.y));
    u.h[1] = __float22bfloat162_rn(make_float2(f0.z, f0.w));
    u.h[2] = __float22bfloat162_rn(make_float2(f1.x, f1.y));
    u.h[3] = __float22bfloat162_rn(make_float2(f1.z, f1.w));
    return u.s8;
}

__device__ __forceinline__ void gload16(const void* g, void* l) {
    __builtin_amdgcn_global_load_lds(
        (const __attribute__((address_space(1))) void*)g,
        (__attribute__((address_space(3))) void*)l, 16, 0, 0);
}

// kprep: [0,1024) W->bf16; [1024,1152) dec_proj; [1152,1664) enc->bf16 (active)
__global__ __launch_bounds__(256) void kprep(
    const float* __restrict__ W, const float* __restrict__ dec,
    const float* __restrict__ enc, const int* __restrict__ seq,
    __hip_bfloat16* __restrict__ Wb, float* __restrict__ dec_proj,
    __hip_bfloat16* __restrict__ encb)
{
    int blk = blockIdx.x, tid = threadIdx.x;
    if (blk < 1024) {
        int idx = (blk * 256 + tid) * 4;   // over H*E
        int h = idx >> 10, e = idx & 1023;
        float4 f = *(const float4*)(W + (size_t)h * 2048 + e);
        __hip_bfloat162 p0 = __float22bfloat162_rn(make_float2(f.x, f.y));
        __hip_bfloat162 p1 = __float22bfloat162_rn(make_float2(f.z, f.w));
        *reinterpret_cast<__hip_bfloat162*>(Wb + idx)     = p0;
        *reinterpret_cast<__hip_bfloat162*>(Wb + idx + 2) = p1;
    } else if (blk < 1152) {
        int gid = (blk - 1024) * 256 + tid;   // 32768 total
        int b = gid >> 10, h = gid & 1023;
        const float4* wd = (const float4*)(W + (size_t)h * 2048 + 1024);
        const float4* dd = (const float4*)(dec + b * 1024);
        float acc = 0.f;
        for (int d = 0; d < 256; ++d) {
            float4 w4 = wd[d], d4 = dd[d];
            acc += w4.x * d4.x + w4.y * d4.y + w4.z * d4.z + w4.w * d4.w;
        }
        dec_proj[gid] = acc;
    } else {
        int g = blk - 1152;           // 512 blocks: 16 s-chunks x 32 b
        int c = g & 15, b = g >> 4;
        if (c * 128 >= seq[b]) return;
        size_t base = ((size_t)b * S + c * 128) * E;
        const float* src = enc + base;
        __hip_bfloat16* dst = encb + base;
        #pragma unroll 4
        for (int it = 0; it < 64; ++it) {
            int idx = it * 2048 + tid * 8;
            float4 f0 = *(const float4*)(src + idx);
            float4 f1 = *(const float4*)(src + idx + 4);
            *(bf16x8_t*)(dst + idx) = cvt8(f0, f1);
        }
    }
}

// K2: 256(s) x 128(h) tile, BK=64, K=1024, 8 waves (4M x 2N), 64x64/wave.
// 3-slot rotating LDS (144 KiB): slot kt%3 holds K-tile kt.
//   A slot: 256 rows x 128B at  slot*32768         (3 x 32 KiB = 96 KiB)
//   B slot: 128 rows x 128B at  98304 + slot*16384 (3 x 16 KiB = 48 KiB)
// 2 phases per K-tile (ks=0,1); phase = {8 ds_read_b128 || stage 3 gload_lds
// of tile kt+2} -> barrier -> lgkmcnt(0) -> setprio(1) -> 16 MFMA ->
// setprio(0) -> [tile end: counted vmcnt BEFORE the barrier] -> barrier.
// SYNC INVARIANT (round-7 fix): a slot is ds_read only after a barrier that
// was preceded (same phase, all waves) by a vmcnt covering that slot's
// gload_lds writes. vmcnt(6) at tile ends (6 loads/thread/tile in flight for
// the *next* tile), vmcnt(0) only at the kt=14 end; prologue vmcnt(6)+barrier.
// XOR-swizzle (row&7)<<4 via pre-swizzled global source + swizzled ds_read.
// Grid 2048: nt=(bid>>3)&7; pair=(bid>>6)*8+(bid&7) -> the 8 nt-blocks of one
// (b,st) are 8 apart in bid -> same XCD -> A-tile L2 reuse.
__global__ __launch_bounds__(512, 2) void k2_mfma8(
    const __hip_bfloat16* __restrict__ encb,
    const __hip_bfloat16* __restrict__ Wb, const float* __restrict__ v,
    const float* __restrict__ dec_proj, const int* __restrict__ seq,
    float* __restrict__ part)
{
    const int bid = blockIdx.x;
    const int nt  = (bid >> 3) & 7;
    const int pair = (bid >> 6) * 8 + (bid & 7);   // 0..255
    const int b   = pair >> 3;
    const int st  = pair & 7;
    const int s0  = st * 256;
    if (s0 >= seq[b]) return;
    const int h0 = nt * 128;

    const int tid  = threadIdx.x;
    const int wave = tid >> 6;
    const int lane = tid & 63;
    const int wr = wave >> 1, wc = wave & 1;   // 4 x 2 wave grid
    const int cr = lane & 15, cg = lane >> 4;

    __shared__ char lds[147456];

    f32x4_t acc[4][4];
    #pragma unroll
    for (int m = 0; m < 4; ++m)
        #pragma unroll
        for (int n = 0; n < 4; ++n)
            acc[m][n] = (f32x4_t){0.f, 0.f, 0.f, 0.f};

    const size_t arowbase = ((size_t)b * S + s0) << 10;

    // A half (128 rows x 64 cols): 2 gload_lds/thread
    auto stageA = [&](int slot, int kt, int half) {
        char* base = lds + slot * 32768 + half * 16384;
        #pragma unroll
        for (int pass = 0; pass < 2; ++pass) {
            const int c = pass * 512 + tid;       // 0..1023
            const int row = c >> 3;               // 0..127
            const int scolb = ((c & 7) * 16) ^ ((row & 7) << 4);
            const __hip_bfloat16* g = encb + arowbase
                + ((size_t)(half * 128 + row) << 10) + kt * 64 + (scolb >> 1);
            gload16(g, base + c * 16);
        }
    };
    // B half (64 rows x 64 cols): 1 gload_lds/thread
    auto stageB = [&](int slot, int kt, int half) {
        char* base = lds + 98304 + slot * 16384 + half * 8192;
        const int c = tid;                        // 0..511
        const int row = c >> 3;                   // 0..63
        const int scolb = ((c & 7) * 16) ^ ((row & 7) << 4);
        const __hip_bfloat16* g = Wb
            + (((size_t)(h0 + half * 64 + row)) << 10) + kt * 64 + (scolb >> 1);
        gload16(g, base + c * 16);
    };

    // prologue: tiles 0 (slot 0) and 1 (slot 1): 12 loads/thread in flight.
    #pragma unroll
    for (int half = 0; half < 2; ++half) { stageA(0, 0, half); stageB(0, 0, half); }
    #pragma unroll
    for (int half = 0; half < 2; ++half) { stageA(1, 1, half); stageB(1, 1, half); }
    // tile 0 landed (oldest 6) for THIS wave; barrier publishes it block-wide.
    asm volatile("s_waitcnt vmcnt(6)" ::: "memory");
    __builtin_amdgcn_s_barrier();

    int cur = 0, stg = 2;
    for (int kt = 0; kt < 16; ++kt) {
        const char* Ab = lds + cur * 32768;
        const char* Bb = lds + 98304 + cur * 16384;
        #pragma unroll
        for (int ks = 0; ks < 2; ++ks) {
            bf16x8_t afr[4], bfr[4];
            #pragma unroll
            for (int m = 0; m < 4; ++m) {
                const int arow  = wr * 64 + m * 16 + cr;
                const int acolb = (ks * 64 + cg * 16) ^ ((arow & 7) << 4);
                afr[m] = *(const bf16x8_t*)(Ab + arow * 128 + acolb);
            }
            #pragma unroll
            for (int n = 0; n < 4; ++n) {
                const int brow  = wc * 64 + n * 16 + cr;
                const int bcolb = (ks * 64 + cg * 16) ^ ((brow & 7) << 4);
                bfr[n] = *(const bf16x8_t*)(Bb + brow * 128 + bcolb);
            }
            if (kt < 14) { stageA(stg, kt + 2, ks); stageB(stg, kt + 2, ks); }
            __builtin_amdgcn_sched_barrier(0);
            __builtin_amdgcn_s_barrier();
            asm volatile("s_waitcnt lgkmcnt(0)" ::: "memory");
            __builtin_amdgcn_sched_barrier(0);
            __builtin_amdgcn_s_setprio(1);
            #pragma unroll
            for (int m = 0; m < 4; ++m)
                #pragma unroll
                for (int n = 0; n < 4; ++n)
                    acc[m][n] = __builtin_amdgcn_mfma_f32_16x16x32_bf16(
                        afr[m], bfr[n], acc[m][n], 0, 0, 0);
            __builtin_amdgcn_s_setprio(0);
            __builtin_amdgcn_sched_barrier(0);
            // Tile boundary: make tile kt+1's loads visible BEFORE the
            // barrier, so next phase's ds_reads are safe for all waves.
            if (ks == 1 && kt < 14)
                asm volatile("s_waitcnt vmcnt(6)" ::: "memory");
            else if (ks == 1 && kt == 14)
                asm volatile("s_waitcnt vmcnt(0)" ::: "memory");
            __builtin_amdgcn_s_barrier();
        }
        cur = (cur == 2) ? 0 : cur + 1;
        stg = (stg == 2) ? 0 : stg + 1;
    }

    // Epilogue: t = v*tanh(acc + dec_proj); reduce over n frags + 16 cr lanes.
    float vv[4], dp[4];
    #pragma unroll
    for (int n = 0; n < 4; ++n) {
        int h = h0 + wc * 64 + n * 16 + cr;
        vv[n] = v[h];
        dp[n] = dec_proj[b * H + h];
    }
    #pragma unroll
    for (int m = 0; m < 4; ++m) {
        #pragma unroll
        for (int j = 0; j < 4; ++j) {
            float t = 0.f;
            #pragma unroll
            for (int n = 0; n < 4; ++n)
                t += vv[n] * fast_tanh(acc[m][n][j] + dp[n]);
            t += __shfl_xor(t, 1);
            t += __shfl_xor(t, 2);
            t += __shfl_xor(t, 4);
            t += __shfl_xor(t, 8);
            if (cr == 0) {
                int srow = s0 + wr * 64 + m * 16 + cg * 4 + j;
                part[(size_t)(b * S + srow) * 16 + nt * 2 + wc] = t;
            }
        }
    }
}

// K2 fallback (ws too small for encb): 256x256 2-phase dbuf, reg-staged A.
__global__ __launch_bounds__(512, 2) void k2_fallback(
    const float* __restrict__ enc, const __hip_bfloat16* __restrict__ Wb,
    const float* __restrict__ v, const float* __restrict__ dec_proj,
    const int* __restrict__ seq, float* __restrict__ part)
{
    const int bid = blockIdx.x;
    const int xcd = bid & 7;
    const int qq  = bid >> 3;
    const int nt  = qq & 3;
    const int pp  = (qq >> 2) * 8 + xcd;
    const int b   = pp >> 3;
    const int st  = pp & 7;
    const int s0  = st * 256;
    if (s0 >= seq[b]) return;
    const int h0 = nt * 256;

    const int tid  = threadIdx.x;
    const int wave = tid >> 6;
    const int lane = tid & 63;
    const int wr = wave >> 2, wc = wave & 3;
    const int cr = lane & 15, cg = lane >> 4;

    __shared__ __hip_bfloat16 Al[2][256 * 64];
    __shared__ __hip_bfloat16 Bl[2][256 * 64];

    const int colb  = (tid & 7) * 16;
    const int rbase = tid >> 3;

    f32x4_t acc[8][4];
    #pragma unroll
    for (int m = 0; m < 8; ++m)
        #pragma unroll
        for (int n = 0; n < 4; ++n)
            acc[m][n] = (f32x4_t){0.f, 0.f, 0.f, 0.f};

    auto stage = [&](int buf, int kt) {
        #pragma unroll
        for (int i = 0; i < 4; ++i) {
            const int row   = i * 64 + rbase;
            const int scolb = colb ^ ((row & 7) << 4);
            const __hip_bfloat16* bg =
                Wb + (((size_t)(h0 + row)) << 10) + kt * 64 + (scolb >> 1);
            gload16(bg, (char*)&Bl[buf][0] + (i * 512 + tid) * 16);
            const float* af =
                enc + (((size_t)b * S + s0 + row) << 10) + kt * 64 + (tid & 7) * 8;
            bf16x8_t v8 = cvt8(*(const float4*)af, *(const float4*)(af + 4));
            *(bf16x8_t*)((char*)&Al[buf][0] + row * 128 + scolb) = v8;
        }
    };

    stage(0, 0);
    __syncthreads();
    int cur = 0;
    for (int kt = 0; kt < 16; ++kt) {
        if (kt < 15) stage(cur ^ 1, kt + 1);
        #pragma unroll
        for (int ks = 0; ks < 2; ++ks) {
            bf16x8_t afr[8], bfr[4];
            #pragma unroll
            for (int m = 0; m < 8; ++m) {
                const int arow  = wr * 128 + m * 16 + cr;
                const int acolb = (ks * 64 + cg * 16) ^ ((arow & 7) << 4);
                afr[m] = *(const bf16x8_t*)((const char*)&Al[cur][0] + arow * 128 + acolb);
            }
            #pragma unroll
            for (int n = 0; n < 4; ++n) {
                const int brow  = wc * 64 + n * 16 + cr;
                const int bcolb = (ks * 64 + cg * 16) ^ ((brow & 7) << 4);
                bfr[n] = *(const bf16x8_t*)((const char*)&Bl[cur][0] + brow * 128 + bcolb);
            }
            #pragma unroll
            for (int m = 0; m < 8; ++m)
                #pragma unroll
                for (int n = 0; n < 4; ++n)
                    acc[m][n] = __builtin_amdgcn_mfma_f32_16x16x32_bf16(
                        afr[m], bfr[n], acc[m][n], 0, 0, 0);
        }
        __syncthreads();
        cur ^= 1;
    }

    float vv[4], dp[4];
    #pragma unroll
    for (int n = 0; n < 4; ++n) {
        int h = h0 + wc * 64 + n * 16 + cr;
        vv[n] = v[h];
        dp[n] = dec_proj[b * H + h];
    }
    #pragma unroll
    for (int m = 0; m < 8; ++m) {
        #pragma unroll
        for (int j = 0; j < 4; ++j) {
            float t = 0.f;
            #pragma unroll
            for (int n = 0; n < 4; ++n)
                t += vv[n] * fast_tanh(acc[m][n][j] + dp[n]);
            t += __shfl_xor(t, 1);
            t += __shfl_xor(t, 2);
            t += __shfl_xor(t, 4);
            t += __shfl_xor(t, 8);
            if (cr == 0) {
                int srow = s0 + wr * 128 + m * 16 + cg * 4 + j;
                part[(size_t)(b * S + srow) * 16 + nt * 4 + wc] = t;
            }
        }
    }
}

// K3: sum 16 partials -> logit; masked softmax over s per batch
__global__ __launch_bounds__(256) void k3_softmax(
    const float* __restrict__ part, const int* __restrict__ seq,
    float* __restrict__ attn)
{
    int b = blockIdx.x, tid = threadIdx.x;
    int len = seq[b];
    float vals[8];
    float mx = -3.4e38f;
    #pragma unroll
    for (int i = 0; i < 8; ++i) {
        int s = i * 256 + tid;
        float x = MASK_VAL;
        if (s < len) {
            const f32x4_t* p = (const f32x4_t*)&part[(size_t)(b * S + s) * 16];
            f32x4_t a = p[0], c = p[1], d = p[2], e = p[3];
            x = (a[0] + a[1] + a[2] + a[3]) + (c[0] + c[1] + c[2] + c[3]) +
                (d[0] + d[1] + d[2] + d[3]) + (e[0] + e[1] + e[2] + e[3]);
        }
        vals[i] = x;
        mx = fmaxf(mx, x);
    }
    #pragma unroll
    for (int off = 1; off < 64; off <<= 1) mx = fmaxf(mx, __shfl_xor(mx, off));
    __shared__ float red[8];
    int wave = tid >> 6, lane = tid & 63;
    if (lane == 0) red[wave] = mx;
    __syncthreads();
    mx = fmaxf(fmaxf(red[0], red[1]), fmaxf(red[2], red[3]));
    float e[8];
    float sum = 0.f;
    #pragma unroll
    for (int i = 0; i < 8; ++i) { e[i] = __expf(vals[i] - mx); sum += e[i]; }
    #pragma unroll
    for (int off = 1; off < 64; off <<= 1) sum += __shfl_xor(sum, off);
    if (lane == 0) red[4 + wave] = sum;
    __syncthreads();
    sum = red[4] + red[5] + red[6] + red[7];
    float inv = 1.0f / sum;
    #pragma unroll
    for (int i = 0; i < 8; ++i) attn[b * S + i * 256 + tid] = e[i] * inv;
}

// K4: opart partial weighted sums over 16 s-chunks of 128.
// AMODE 0: bf16 encb; AMODE 1: fp32 enc.
template<int AMODE>
__global__ __launch_bounds__(256) void k4_partial(
    const float* __restrict__ enc, const __hip_bfloat16* __restrict__ encb,
    const float* __restrict__ attn, const int* __restrict__ seq,
    float* __restrict__ opart)
{
    int c = blockIdx.x, b = blockIdx.y, tid = threadIdx.x;
    int base_s = c * 128;
    int len = seq[b];
    if (AMODE == 0) {
        int e0 = (tid & 127) * 8;
        int so = tid >> 7;
        float av[8];
        #pragma unroll
        for (int j = 0; j < 8; ++j) av[j] = 0.f;
        if (base_s < len) {
            int s_end = min(128, len - base_s);
            for (int s = so; s < s_end; s += 2) {
                float w = attn[b * S + base_s + s];
                bf16x8_t u = *(const bf16x8_t*)(encb +
                    (((size_t)b * S + base_s + s) << 10) + e0);
                #pragma unroll
                for (int j = 0; j < 8; ++j) av[j] += w * b2f(u[j]);
            }
        }
        float* dst = opart + (((size_t)(b * 16 + c) * 2 + so) << 10) + e0;
        *(float4*)dst       = make_float4(av[0], av[1], av[2], av[3]);
        *(float4*)(dst + 4) = make_float4(av[4], av[5], av[6], av[7]);
    } else {
        float4 acc = make_float4(0.f, 0.f, 0.f, 0.f);
        if (base_s < len) {
            int s_end = min(128, len - base_s);
            const float* ep = enc + ((size_t)b * S + base_s) * E + (tid & 255) * 4;
            const float* ap = attn + b * S + base_s;
            for (int s = 0; s < s_end; ++s) {
                float w = ap[s];
                float4 ev = *(const float4*)ep;
                ep += E;
                acc.x += w * ev.x; acc.y += w * ev.y;
                acc.z += w * ev.z; acc.w += w * ev.w;
            }
        }
        float* dst = opart + (((size_t)(b * 16 + c) * 2) << 10) + tid * 4;
        *(float4*)dst = acc;
        float* dst2 = opart + (((size_t)(b * 16 + c) * 2 + 1) << 10) + tid * 4;
        *(float4*)dst2 = make_float4(0.f, 0.f, 0.f, 0.f);
    }
}

// K5: out[b][e] = sum over 32 partials
__global__ __launch_bounds__(256) void k5_reduce(
    const float* __restrict__ opart, float* __restrict__ out)
{
    int gid = blockIdx.x * 256 + threadIdx.x;  // 32768 = B*E
    int b = gid >> 10, e = gid & 1023;
    float s = 0.f;
    #pragma unroll
    for (int c = 0; c < 32; ++c) s += opart[((size_t)(b * 32 + c) << 10) + e];
    out[gid] = s;
}

extern "C" void kernel_launch(void* const* d_in, const int* in_sizes, int n_in,
                              void* d_out, int out_size, void* d_ws, size_t ws_size,
                              hipStream_t stream)
{
    const float* enc = (const float*)d_in[0];
    const int*   seq = (const int*)d_in[1];
    const float* dec = (const float*)d_in[2];
    const float* W   = (const float*)d_in[3];
    const float* v   = (const float*)d_in[4];

    float* out  = (float*)d_out;            // (B, E)
    float* attn = out + B * E;              // (B, S)

    float* dec_proj = (float*)d_ws;                         // B*H
    float* part     = dec_proj + B * H;                     // B*S*16
    float* opart    = part + (size_t)B * S * 16;            // B*32*1024
    __hip_bfloat16* Wb = (__hip_bfloat16*)(opart + (size_t)B * 32 * 1024);
    __hip_bfloat16* encb = Wb + (size_t)H * E;              // B*S*E bf16

    const size_t need = (size_t)(B * H + B * S * 16 + B * 32 * 1024) * 4
                      + (size_t)H * E * 2 + (size_t)B * S * E * 2;
    const bool use_encb = ws_size >= need;

    if (use_encb) {
        hipLaunchKernelGGL(kprep, dim3(1664), dim3(256), 0, stream,
                           W, dec, enc, seq, Wb, dec_proj, encb);
        hipLaunchKernelGGL(k2_mfma8, dim3(2048), dim3(512), 0, stream,
                           encb, Wb, v, dec_proj, seq, part);
    } else {
        hipLaunchKernelGGL(kprep, dim3(1152), dim3(256), 0, stream,
                           W, dec, enc, seq, Wb, dec_proj, encb);
        hipLaunchKernelGGL(k2_fallback, dim3(1024), dim3(512), 0, stream,
                           enc, Wb, v, dec_proj, seq, part);
    }
    hipLaunchKernelGGL(k3_softmax, dim3(B), dim3(256), 0, stream,
                       part, seq, attn);
    if (use_encb) {
        hipLaunchKernelGGL(k4_partial<0>, dim3(16, B), dim3(256), 0, stream,
                           enc, encb, attn, seq, opart);
    } else {
        hipLaunchKernelGGL(k4_partial<1>, dim3(16, B), dim3(256), 0, stream,
                           enc, encb, attn, seq, opart);
    }
    hipLaunchKernelGGL(k5_reduce, dim3(B * E / 256), dim3(256), 0, stream,
                       opart, out);
}

// Round 9
// 245.733 us; speedup vs baseline: 1.2444x; 1.2326x over previous
//
#include <hip/hip_runtime.h>
#include <hip/hip_bf16.h>

#define B 32
#define S 2048
#define E 1024
#define H 1024
#define MASK_VAL -50000.0f

typedef __attribute__((ext_vector_type(8))) short bf16x8_t;
typedef __attribute__((ext_vector_type(4))) float f32x4_t;

__device__ __forceinline__ float fast_tanh(float x) {
    float a = fabsf(x);
    float e = __expf(-2.0f * a);
    float t = (1.0f - e) / (1.0f + e);
    return copysignf(t, x);
}

__device__ __forceinline__ bf16x8_t cvt8(const float4 f0, const float4 f1) {
    union { bf16x8_t s8; __hip_bfloat162 h[4]; } u;
    u.h[0] = __float22bfloat162_rn(make_float2(f0.x, f0.y));
    u.h[1] = __float22bfloat162_rn(make_float2(f0.z, f0.w));
    u.h[2] = __float22bfloat162_rn(make_float2(f1.x, f1.y));
    u.h[3] = __float22bfloat162_rn(make_float2(f1.z, f1.w));
    return u.s8;
}

__device__ __forceinline__ void gload16(const void* g, void* l) {
    __builtin_amdgcn_global_load_lds(
        (const __attribute__((address_space(1))) void*)g,
        (__attribute__((address_space(3))) void*)l, 16, 0, 0);
}

// kprep: [0,1024) W[:, :1024] -> bf16 Wb; [1024,1152) dec_proj
__global__ __launch_bounds__(256) void kprep(
    const float* __restrict__ W, const float* __restrict__ dec,
    __hip_bfloat16* __restrict__ Wb, float* __restrict__ dec_proj)
{
    int blk = blockIdx.x, tid = threadIdx.x;
    if (blk < 1024) {
        int idx = (blk * 256 + tid) * 4;   // over H*E
        int h = idx >> 10, e = idx & 1023;
        float4 f = *(const float4*)(W + (size_t)h * 2048 + e);
        __hip_bfloat162 p0 = __float22bfloat162_rn(make_float2(f.x, f.y));
        __hip_bfloat162 p1 = __float22bfloat162_rn(make_float2(f.z, f.w));
        *reinterpret_cast<__hip_bfloat162*>(Wb + idx)     = p0;
        *reinterpret_cast<__hip_bfloat162*>(Wb + idx + 2) = p1;
    } else {
        int gid = (blk - 1024) * 256 + tid;   // 32768 total
        int b = gid >> 10, h = gid & 1023;
        const float4* wd = (const float4*)(W + (size_t)h * 2048 + 1024);
        const float4* dd = (const float4*)(dec + b * 1024);
        float acc = 0.f;
        for (int d = 0; d < 256; ++d) {
            float4 w4 = wd[d], d4 = dd[d];
            acc += w4.x * d4.x + w4.y * d4.y + w4.z * d4.z + w4.w * d4.w;
        }
        dec_proj[gid] = acc;
    }
}

// K2: 128(s) x 128(h) tile, BK=64, K=1024, 4 waves (2x2), 64x64/wave.
// Round-4 proven 2-phase double-buffer: stage(next) issued BEFORE the
// ds_read+MFMA of cur; the single per-iter __syncthreads (compiler emits
// vmcnt(0)+lgkmcnt(0) there) lands AFTER the MFMAs, so next-tile loads fly
// under the compute. A is reg-staged from fp32 enc (global float4 x2 -> cvt
// -> swizzled ds_write_b128) -- no enc->bf16 prep pass needed. B via
// global_load_lds from bf16 Wb (linear LDS dest, pre-swizzled global src).
// XOR-swizzle byte col ^= (row&7)<<4 -> stride-128B ds_read_b128 is 2-way
// (free). LDS 64 KiB -> 2 blocks/CU.
// Grid 4096 flattened: pair=(bid>>6)*8+(bid&7); ht=(bid>>3)&7 -> the 8
// ht-blocks of one (b,st) are 8 apart -> same XCD -> A-tile L2 reuse.
__global__ __launch_bounds__(256, 2) void k2_mfma(
    const float* __restrict__ enc, const __hip_bfloat16* __restrict__ Wb,
    const float* __restrict__ v, const float* __restrict__ dec_proj,
    const int* __restrict__ seq, float* __restrict__ part)
{
    const int bid  = blockIdx.x;
    const int pair = (bid >> 6) * 8 + (bid & 7);   // 0..511 = 16 s-tiles x 32 b
    const int ht   = (bid >> 3) & 7;
    const int b    = pair >> 4;
    const int s0   = (pair & 15) * 128;
    if (s0 >= seq[b]) return;
    const int h0 = ht * 128;

    const int tid  = threadIdx.x;
    const int wave = tid >> 6;
    const int lane = tid & 63;
    const int wr = wave >> 1, wc = wave & 1;   // 2x2 wave grid
    const int cr = lane & 15, cg = lane >> 4;

    __shared__ __hip_bfloat16 Al[2][128 * 64];
    __shared__ __hip_bfloat16 Bl[2][128 * 64];

    const int colb  = (tid & 7) * 16;   // byte col within 128B LDS row
    const int rbase = tid >> 3;         // 0..31

    f32x4_t acc[4][4];
    #pragma unroll
    for (int m = 0; m < 4; ++m)
        #pragma unroll
        for (int n = 0; n < 4; ++n)
            acc[m][n] = (f32x4_t){0.f, 0.f, 0.f, 0.f};

    auto stage = [&](int buf, int kt) {
        #pragma unroll
        for (int i = 0; i < 4; ++i) {
            const int row   = i * 32 + rbase;
            const int scolb = colb ^ ((row & 7) << 4);
            const __hip_bfloat16* bg =
                Wb + (((size_t)(h0 + row)) << 10) + kt * 64 + (scolb >> 1);
            gload16(bg, (char*)&Bl[buf][0] + (i * 256 + tid) * 16);
            const float* af =
                enc + (((size_t)b * S + s0 + row) << 10) + kt * 64 + (tid & 7) * 8;
            bf16x8_t v8 = cvt8(*(const float4*)af, *(const float4*)(af + 4));
            *(bf16x8_t*)((char*)&Al[buf][0] + row * 128 + scolb) = v8;
        }
    };

    stage(0, 0);
    __syncthreads();
    int cur = 0;
    for (int kt = 0; kt < 16; ++kt) {
        if (kt < 15) stage(cur ^ 1, kt + 1);   // flies under the MFMAs below
        bf16x8_t afr[2][4], bfr[2][4];
        #pragma unroll
        for (int ks = 0; ks < 2; ++ks) {
            #pragma unroll
            for (int m = 0; m < 4; ++m) {
                const int arow  = wr * 64 + m * 16 + cr;
                const int acolb = (ks * 64 + cg * 16) ^ ((arow & 7) << 4);
                afr[ks][m] = *(const bf16x8_t*)((const char*)&Al[cur][0] + arow * 128 + acolb);
                const int brow  = wc * 64 + m * 16 + cr;
                const int bcolb = (ks * 64 + cg * 16) ^ ((brow & 7) << 4);
                bfr[ks][m] = *(const bf16x8_t*)((const char*)&Bl[cur][0] + brow * 128 + bcolb);
            }
        }
        #pragma unroll
        for (int ks = 0; ks < 2; ++ks)
            #pragma unroll
            for (int m = 0; m < 4; ++m)
                #pragma unroll
                for (int n = 0; n < 4; ++n)
                    acc[m][n] = __builtin_amdgcn_mfma_f32_16x16x32_bf16(
                        afr[ks][m], bfr[ks][n], acc[m][n], 0, 0, 0);
        __syncthreads();   // drains vmcnt+lgkmcnt: next buf ready, cur consumed
        cur ^= 1;
    }

    // Epilogue: t = v*tanh(acc + dec_proj); reduce over n frags + 16 cr lanes.
    float vv[4], dp[4];
    #pragma unroll
    for (int n = 0; n < 4; ++n) {
        int h = h0 + wc * 64 + n * 16 + cr;
        vv[n] = v[h];
        dp[n] = dec_proj[b * H + h];
    }
    #pragma unroll
    for (int m = 0; m < 4; ++m) {
        #pragma unroll
        for (int j = 0; j < 4; ++j) {
            float t = 0.f;
            #pragma unroll
            for (int n = 0; n < 4; ++n)
                t += vv[n] * fast_tanh(acc[m][n][j] + dp[n]);
            t += __shfl_xor(t, 1);
            t += __shfl_xor(t, 2);
            t += __shfl_xor(t, 4);
            t += __shfl_xor(t, 8);
            if (cr == 0) {
                int srow = s0 + wr * 64 + m * 16 + cg * 4 + j;
                part[(size_t)(b * S + srow) * 16 + ht * 2 + wc] = t;
            }
        }
    }
}

// K3: sum 16 partials -> logit; masked softmax over s per batch
__global__ __launch_bounds__(256) void k3_softmax(
    const float* __restrict__ part, const int* __restrict__ seq,
    float* __restrict__ attn)
{
    int b = blockIdx.x, tid = threadIdx.x;
    int len = seq[b];
    float vals[8];
    float mx = -3.4e38f;
    #pragma unroll
    for (int i = 0; i < 8; ++i) {
        int s = i * 256 + tid;
        float x = MASK_VAL;
        if (s < len) {
            const f32x4_t* p = (const f32x4_t*)&part[(size_t)(b * S + s) * 16];
            f32x4_t a = p[0], c = p[1], d = p[2], e = p[3];
            x = (a[0] + a[1] + a[2] + a[3]) + (c[0] + c[1] + c[2] + c[3]) +
                (d[0] + d[1] + d[2] + d[3]) + (e[0] + e[1] + e[2] + e[3]);
        }
        vals[i] = x;
        mx = fmaxf(mx, x);
    }
    #pragma unroll
    for (int off = 1; off < 64; off <<= 1) mx = fmaxf(mx, __shfl_xor(mx, off));
    __shared__ float red[8];
    int wave = tid >> 6, lane = tid & 63;
    if (lane == 0) red[wave] = mx;
    __syncthreads();
    mx = fmaxf(fmaxf(red[0], red[1]), fmaxf(red[2], red[3]));
    float e[8];
    float sum = 0.f;
    #pragma unroll
    for (int i = 0; i < 8; ++i) { e[i] = __expf(vals[i] - mx); sum += e[i]; }
    #pragma unroll
    for (int off = 1; off < 64; off <<= 1) sum += __shfl_xor(sum, off);
    if (lane == 0) red[4 + wave] = sum;
    __syncthreads();
    sum = red[4] + red[5] + red[6] + red[7];
    float inv = 1.0f / sum;
    #pragma unroll
    for (int i = 0; i < 8; ++i) attn[b * S + i * 256 + tid] = e[i] * inv;
}

// K4: opart[b][c][e] = sum_{s in 128-chunk c} attn[b][s] * enc[b][s][e]
__global__ __launch_bounds__(256) void k4_partial(
    const float* __restrict__ enc, const float* __restrict__ attn,
    const int* __restrict__ seq, float* __restrict__ opart)
{
    int c = blockIdx.x, b = blockIdx.y, tid = threadIdx.x;
    int base_s = c * 128;
    int len = seq[b];
    float4 acc = make_float4(0.f, 0.f, 0.f, 0.f);
    if (base_s < len) {
        int s_end = min(128, len - base_s);
        const float* ep = enc + (((size_t)b * S + base_s) << 10) + tid * 4;
        const float* ap = attn + b * S + base_s;
        for (int s = 0; s < s_end; ++s) {
            float w = ap[s];
            float4 ev = *(const float4*)ep;
            ep += E;
            acc.x += w * ev.x; acc.y += w * ev.y;
            acc.z += w * ev.z; acc.w += w * ev.w;
        }
    }
    *(float4*)(&opart[(((size_t)(b * 16 + c)) << 10) + tid * 4]) = acc;
}

// K5: out[b][e] = sum over 16 partials
__global__ __launch_bounds__(256) void k5_reduce(
    const float* __restrict__ opart, float* __restrict__ out)
{
    int gid = blockIdx.x * 256 + threadIdx.x;  // 32768 = B*E
    int b = gid >> 10, e = gid & 1023;
    float s = 0.f;
    #pragma unroll
    for (int c = 0; c < 16; ++c) s += opart[((size_t)(b * 16 + c) << 10) + e];
    out[gid] = s;
}

extern "C" void kernel_launch(void* const* d_in, const int* in_sizes, int n_in,
                              void* d_out, int out_size, void* d_ws, size_t ws_size,
                              hipStream_t stream)
{
    const float* enc = (const float*)d_in[0];
    const int*   seq = (const int*)d_in[1];
    const float* dec = (const float*)d_in[2];
    const float* W   = (const float*)d_in[3];
    const float* v   = (const float*)d_in[4];

    float* out  = (float*)d_out;            // (B, E)
    float* attn = out + B * E;              // (B, S)

    float* dec_proj = (float*)d_ws;                         // B*H
    float* part     = dec_proj + B * H;                     // B*S*16
    float* opart    = part + (size_t)B * S * 16;            // B*16*1024
    __hip_bfloat16* Wb = (__hip_bfloat16*)(opart + (size_t)B * 16 * 1024);

    hipLaunchKernelGGL(kprep, dim3(1152), dim3(256), 0, stream,
                       W, dec, Wb, dec_proj);
    hipLaunchKernelGGL(k2_mfma, dim3(4096), dim3(256), 0, stream,
                       enc, Wb, v, dec_proj, seq, part);
    hipLaunchKernelGGL(k3_softmax, dim3(B), dim3(256), 0, stream,
                       part, seq, attn);
    hipLaunchKernelGGL(k4_partial, dim3(16, B), dim3(256), 0, stream,
                       enc, attn, seq, opart);
    hipLaunchKernelGGL(k5_reduce, dim3(B * E / 256), dim3(256), 0, stream,
                       opart, out);
}

// Round 10
// 245.629 us; speedup vs baseline: 1.2449x; 1.0004x over previous
//
#include <hip/hip_runtime.h>
#include <hip/hip_bf16.h>

#define B 32
#define S 2048
#define E 1024
#define H 1024
#define MASK_VAL -50000.0f

typedef __attribute__((ext_vector_type(8))) short bf16x8_t;
typedef __attribute__((ext_vector_type(4))) float f32x4_t;

__device__ __forceinline__ float fast_tanh(float x) {
    float a = fabsf(x);
    float e = __expf(-2.0f * a);
    float t = (1.0f - e) / (1.0f + e);
    return copysignf(t, x);
}

__device__ __forceinline__ float b2f(short s) {
    return __uint_as_float(((unsigned)(unsigned short)s) << 16);
}

__device__ __forceinline__ bf16x8_t cvt8(const float4 f0, const float4 f1) {
    union { bf16x8_t s8; __hip_bfloat162 h[4]; } u;
    u.h[0] = __float22bfloat162_rn(make_float2(f0.x, f0.y));
    u.h[1] = __float22bfloat162_rn(make_float2(f0.z, f0.w));
    u.h[2] = __float22bfloat162_rn(make_float2(f1.x, f1.y));
    u.h[3] = __float22bfloat162_rn(make_float2(f1.z, f1.w));
    return u.s8;
}

__device__ __forceinline__ void gload16(const void* g, void* l) {
    __builtin_amdgcn_global_load_lds(
        (const __attribute__((address_space(1))) void*)g,
        (__attribute__((address_space(3))) void*)l, 16, 0, 0);
}

// kprep: [0,1024) W[:, :1024] -> bf16 Wb (coalesced);
//        [1024,2048) dec_proj, one h per block: coalesced W_dec row -> LDS,
//        32 b-dots with 8-lane chunk reduce (fixes the 8KB-stride GEMV).
__global__ __launch_bounds__(256) void kprep(
    const float* __restrict__ W, const float* __restrict__ dec,
    __hip_bfloat16* __restrict__ Wb, float* __restrict__ dec_proj)
{
    int blk = blockIdx.x, tid = threadIdx.x;
    if (blk < 1024) {
        int idx = (blk * 256 + tid) * 4;   // over H*E
        int h = idx >> 10, e = idx & 1023;
        float4 f = *(const float4*)(W + (size_t)h * 2048 + e);
        __hip_bfloat162 p0 = __float22bfloat162_rn(make_float2(f.x, f.y));
        __hip_bfloat162 p1 = __float22bfloat162_rn(make_float2(f.z, f.w));
        *reinterpret_cast<__hip_bfloat162*>(Wb + idx)     = p0;
        *reinterpret_cast<__hip_bfloat162*>(Wb + idx + 2) = p1;
    } else {
        int h = blk - 1024;                 // 0..1023
        __shared__ float4 wlds[256];
        wlds[tid] = *(const float4*)(W + (size_t)h * 2048 + 1024 + tid * 4);
        __syncthreads();
        int b = tid >> 3, chunk = tid & 7;  // 32 b x 8 chunks of 128 elems
        const float4* dd = (const float4*)(dec + b * 1024 + chunk * 128);
        float acc = 0.f;
        #pragma unroll
        for (int i = 0; i < 32; ++i) {
            float4 w4 = wlds[chunk * 32 + i];
            float4 d4 = dd[i];
            acc += w4.x * d4.x + w4.y * d4.y + w4.z * d4.z + w4.w * d4.w;
        }
        acc += __shfl_xor(acc, 1);
        acc += __shfl_xor(acc, 2);
        acc += __shfl_xor(acc, 4);
        if (chunk == 0) dec_proj[b * H + h] = acc;
    }
}

// K2: 128(s) x 128(h) tile, BK=64, K=1024, 4 waves (2x2), 64x64/wave.
// Proven 2-phase double-buffer (round 4): stage(next) issued BEFORE
// ds_read+MFMA(cur); single per-iter __syncthreads drains vmcnt after MFMAs.
// XOR-swizzle byte col ^= (row&7)<<4. LDS 64 KiB -> 2 blocks/CU.
// MODE 0: A via global_load_lds from encb (fast path), ht=1..7.
//         grid 3584: xcd=bid&7, j=bid>>3, pair=(j/7)*8+xcd, ht=j%7+1
//         -> the 7 blocks of one pair share an XCD (A-tile L2 reuse).
// MODE 1: ht=0, grid 512 (bid=pair): A reg-staged from fp32 enc and the
//         converted bf16 written to encb (linear, coalesced) as a side
//         effect -- replaces the separate enc->bf16 conversion pass.
// MODE 2: fallback (no encb ws): reg-staged A for all ht, grid 4096.
template<int MODE>
__global__ __launch_bounds__(256, 2) void k2_mfma(
    const float* __restrict__ enc, __hip_bfloat16* __restrict__ encb,
    const __hip_bfloat16* __restrict__ Wb, const float* __restrict__ v,
    const float* __restrict__ dec_proj, const int* __restrict__ seq,
    float* __restrict__ part)
{
    const int bid = blockIdx.x;
    int pair, ht;
    if (MODE == 1) {
        pair = bid; ht = 0;
    } else if (MODE == 0) {
        const int xcd = bid & 7, j = bid >> 3;
        pair = (j / 7) * 8 + xcd; ht = j % 7 + 1;
    } else {
        pair = (bid >> 6) * 8 + (bid & 7); ht = (bid >> 3) & 7;
    }
    const int b  = pair >> 4;
    const int s0 = (pair & 15) * 128;
    if (s0 >= seq[b]) return;
    const int h0 = ht * 128;

    const int tid  = threadIdx.x;
    const int wave = tid >> 6;
    const int lane = tid & 63;
    const int wr = wave >> 1, wc = wave & 1;   // 2x2 wave grid
    const int cr = lane & 15, cg = lane >> 4;

    __shared__ __hip_bfloat16 Al[2][128 * 64];
    __shared__ __hip_bfloat16 Bl[2][128 * 64];

    const int colb  = (tid & 7) * 16;   // byte col within 128B LDS row
    const int rbase = tid >> 3;         // 0..31

    f32x4_t acc[4][4];
    #pragma unroll
    for (int m = 0; m < 4; ++m)
        #pragma unroll
        for (int n = 0; n < 4; ++n)
            acc[m][n] = (f32x4_t){0.f, 0.f, 0.f, 0.f};

    auto stage = [&](int buf, int kt) {
        #pragma unroll
        for (int i = 0; i < 4; ++i) {
            const int row   = i * 32 + rbase;
            const int scolb = colb ^ ((row & 7) << 4);
            const __hip_bfloat16* bg =
                Wb + (((size_t)(h0 + row)) << 10) + kt * 64 + (scolb >> 1);
            gload16(bg, (char*)&Bl[buf][0] + (i * 256 + tid) * 16);
            if (MODE == 0) {
                const __hip_bfloat16* ag =
                    encb + (((size_t)b * S + s0 + row) << 10) + kt * 64 + (scolb >> 1);
                gload16(ag, (char*)&Al[buf][0] + (i * 256 + tid) * 16);
            } else {
                const size_t aoff = (((size_t)b * S + s0 + row) << 10)
                                  + kt * 64 + (tid & 7) * 8;
                const float* af = enc + aoff;
                bf16x8_t v8 = cvt8(*(const float4*)af, *(const float4*)(af + 4));
                *(bf16x8_t*)((char*)&Al[buf][0] + row * 128 + scolb) = v8;
                if (MODE == 1)
                    *(bf16x8_t*)(encb + aoff) = v8;   // linear, coalesced
            }
        }
    };

    stage(0, 0);
    __syncthreads();
    int cur = 0;
    for (int kt = 0; kt < 16; ++kt) {
        if (kt < 15) stage(cur ^ 1, kt + 1);   // flies under the MFMAs below
        bf16x8_t afr[2][4], bfr[2][4];
        #pragma unroll
        for (int ks = 0; ks < 2; ++ks) {
            #pragma unroll
            for (int m = 0; m < 4; ++m) {
                const int arow  = wr * 64 + m * 16 + cr;
                const int acolb = (ks * 64 + cg * 16) ^ ((arow & 7) << 4);
                afr[ks][m] = *(const bf16x8_t*)((const char*)&Al[cur][0] + arow * 128 + acolb);
                const int brow  = wc * 64 + m * 16 + cr;
                const int bcolb = (ks * 64 + cg * 16) ^ ((brow & 7) << 4);
                bfr[ks][m] = *(const bf16x8_t*)((const char*)&Bl[cur][0] + brow * 128 + bcolb);
            }
        }
        #pragma unroll
        for (int ks = 0; ks < 2; ++ks)
            #pragma unroll
            for (int m = 0; m < 4; ++m)
                #pragma unroll
                for (int n = 0; n < 4; ++n)
                    acc[m][n] = __builtin_amdgcn_mfma_f32_16x16x32_bf16(
                        afr[ks][m], bfr[ks][n], acc[m][n], 0, 0, 0);
        __syncthreads();   // drains vmcnt+lgkmcnt: next buf ready, cur consumed
        cur ^= 1;
    }

    // Epilogue: t = v*tanh(acc + dec_proj); reduce over n frags + 16 cr lanes.
    float vv[4], dp[4];
    #pragma unroll
    for (int n = 0; n < 4; ++n) {
        int h = h0 + wc * 64 + n * 16 + cr;
        vv[n] = v[h];
        dp[n] = dec_proj[b * H + h];
    }
    #pragma unroll
    for (int m = 0; m < 4; ++m) {
        #pragma unroll
        for (int j = 0; j < 4; ++j) {
            float t = 0.f;
            #pragma unroll
            for (int n = 0; n < 4; ++n)
                t += vv[n] * fast_tanh(acc[m][n][j] + dp[n]);
            t += __shfl_xor(t, 1);
            t += __shfl_xor(t, 2);
            t += __shfl_xor(t, 4);
            t += __shfl_xor(t, 8);
            if (cr == 0) {
                int srow = s0 + wr * 64 + m * 16 + cg * 4 + j;
                part[(size_t)(b * S + srow) * 16 + ht * 2 + wc] = t;
            }
        }
    }
}

// K3: sum 16 partials -> logit; masked softmax over s per batch
__global__ __launch_bounds__(256) void k3_softmax(
    const float* __restrict__ part, const int* __restrict__ seq,
    float* __restrict__ attn)
{
    int b = blockIdx.x, tid = threadIdx.x;
    int len = seq[b];
    float vals[8];
    float mx = -3.4e38f;
    #pragma unroll
    for (int i = 0; i < 8; ++i) {
        int s = i * 256 + tid;
        float x = MASK_VAL;
        if (s < len) {
            const f32x4_t* p = (const f32x4_t*)&part[(size_t)(b * S + s) * 16];
            f32x4_t a = p[0], c = p[1], d = p[2], e = p[3];
            x = (a[0] + a[1] + a[2] + a[3]) + (c[0] + c[1] + c[2] + c[3]) +
                (d[0] + d[1] + d[2] + d[3]) + (e[0] + e[1] + e[2] + e[3]);
        }
        vals[i] = x;
        mx = fmaxf(mx, x);
    }
    #pragma unroll
    for (int off = 1; off < 64; off <<= 1) mx = fmaxf(mx, __shfl_xor(mx, off));
    __shared__ float red[8];
    int wave = tid >> 6, lane = tid & 63;
    if (lane == 0) red[wave] = mx;
    __syncthreads();
    mx = fmaxf(fmaxf(red[0], red[1]), fmaxf(red[2], red[3]));
    float e[8];
    float sum = 0.f;
    #pragma unroll
    for (int i = 0; i < 8; ++i) { e[i] = __expf(vals[i] - mx); sum += e[i]; }
    #pragma unroll
    for (int off = 1; off < 64; off <<= 1) sum += __shfl_xor(sum, off);
    if (lane == 0) red[4 + wave] = sum;
    __syncthreads();
    sum = red[4] + red[5] + red[6] + red[7];
    float inv = 1.0f / sum;
    #pragma unroll
    for (int i = 0; i < 8; ++i) attn[b * S + i * 256 + tid] = e[i] * inv;
}

// K4: opart partial weighted sums over 16 s-chunks of 128, 2-way s-split.
// AMODE 0: bf16 encb (active rows written by k2<1>); AMODE 1: fp32 enc.
template<int AMODE>
__global__ __launch_bounds__(256) void k4_partial(
    const float* __restrict__ enc, const __hip_bfloat16* __restrict__ encb,
    const float* __restrict__ attn, const int* __restrict__ seq,
    float* __restrict__ opart)
{
    int c = blockIdx.x, b = blockIdx.y, tid = threadIdx.x;
    int base_s = c * 128;
    int len = seq[b];
    if (AMODE == 0) {
        int e0 = (tid & 127) * 8;
        int so = tid >> 7;
        float av[8];
        #pragma unroll
        for (int j = 0; j < 8; ++j) av[j] = 0.f;
        if (base_s < len) {
            int s_end = min(128, len - base_s);
            for (int s = so; s < s_end; s += 2) {
                float w = attn[b * S + base_s + s];
                bf16x8_t u = *(const bf16x8_t*)(encb +
                    (((size_t)b * S + base_s + s) << 10) + e0);
                #pragma unroll
                for (int j = 0; j < 8; ++j) av[j] += w * b2f(u[j]);
            }
        }
        float* dst = opart + (((size_t)(b * 16 + c) * 2 + so) << 10) + e0;
        *(float4*)dst       = make_float4(av[0], av[1], av[2], av[3]);
        *(float4*)(dst + 4) = make_float4(av[4], av[5], av[6], av[7]);
    } else {
        float4 acc = make_float4(0.f, 0.f, 0.f, 0.f);
        if (base_s < len) {
            int s_end = min(128, len - base_s);
            const float* ep = enc + (((size_t)b * S + base_s) << 10) + tid * 4;
            const float* ap = attn + b * S + base_s;
            for (int s = 0; s < s_end; ++s) {
                float w = ap[s];
                float4 ev = *(const float4*)ep;
                ep += E;
                acc.x += w * ev.x; acc.y += w * ev.y;
                acc.z += w * ev.z; acc.w += w * ev.w;
            }
        }
        float* dst = opart + (((size_t)(b * 16 + c) * 2) << 10) + tid * 4;
        *(float4*)dst = acc;
        float* dst2 = opart + (((size_t)(b * 16 + c) * 2 + 1) << 10) + tid * 4;
        *(float4*)dst2 = make_float4(0.f, 0.f, 0.f, 0.f);
    }
}

// K5: out[b][e] = sum over 32 partials
__global__ __launch_bounds__(256) void k5_reduce(
    const float* __restrict__ opart, float* __restrict__ out)
{
    int gid = blockIdx.x * 256 + threadIdx.x;  // 32768 = B*E
    int b = gid >> 10, e = gid & 1023;
    float s = 0.f;
    #pragma unroll
    for (int c = 0; c < 32; ++c) s += opart[((size_t)(b * 32 + c) << 10) + e];
    out[gid] = s;
}

extern "C" void kernel_launch(void* const* d_in, const int* in_sizes, int n_in,
                              void* d_out, int out_size, void* d_ws, size_t ws_size,
                              hipStream_t stream)
{
    const float* enc = (const float*)d_in[0];
    const int*   seq = (const int*)d_in[1];
    const float* dec = (const float*)d_in[2];
    const float* W   = (const float*)d_in[3];
    const float* v   = (const float*)d_in[4];

    float* out  = (float*)d_out;            // (B, E)
    float* attn = out + B * E;              // (B, S)

    float* dec_proj = (float*)d_ws;                         // B*H
    float* part     = dec_proj + B * H;                     // B*S*16
    float* opart    = part + (size_t)B * S * 16;            // B*32*1024
    __hip_bfloat16* Wb = (__hip_bfloat16*)(opart + (size_t)B * 32 * 1024);
    __hip_bfloat16* encb = Wb + (size_t)H * E;              // B*S*E bf16

    const size_t need = (size_t)(B * H + B * S * 16 + B * 32 * 1024) * 4
                      + (size_t)H * E * 2 + (size_t)B * S * E * 2;
    const bool use_encb = ws_size >= need;

    hipLaunchKernelGGL(kprep, dim3(2048), dim3(256), 0, stream,
                       W, dec, Wb, dec_proj);
    if (use_encb) {
        hipLaunchKernelGGL(k2_mfma<1>, dim3(512), dim3(256), 0, stream,
                           enc, encb, Wb, v, dec_proj, seq, part);
        hipLaunchKernelGGL(k2_mfma<0>, dim3(3584), dim3(256), 0, stream,
                           enc, encb, Wb, v, dec_proj, seq, part);
    } else {
        hipLaunchKernelGGL(k2_mfma<2>, dim3(4096), dim3(256), 0, stream,
                           enc, encb, Wb, v, dec_proj, seq, part);
    }
    hipLaunchKernelGGL(k3_softmax, dim3(B), dim3(256), 0, stream,
                       part, seq, attn);
    if (use_encb) {
        hipLaunchKernelGGL(k4_partial<0>, dim3(16, B), dim3(256), 0, stream,
                           enc, encb, attn, seq, opart);
    } else {
        hipLaunchKernelGGL(k4_partial<1>, dim3(16, B), dim3(256), 0, stream,
                           enc, encb, attn, seq, opart);
    }
    hipLaunchKernelGGL(k5_reduce, dim3(B * E / 256), dim3(256), 0, stream,
                       opart, out);
}

// Round 11
// 223.825 us; speedup vs baseline: 1.3661x; 1.0974x over previous
//
#include <hip/hip_runtime.h>
#include <hip/hip_bf16.h>

#define B 32
#define S 2048
#define E 1024
#define H 1024
#define MASK_VAL -50000.0f

typedef __attribute__((ext_vector_type(8))) short bf16x8_t;
typedef __attribute__((ext_vector_type(4))) float f32x4_t;

__device__ __forceinline__ float fast_tanh(float x) {
    float a = fabsf(x);
    float e = __expf(-2.0f * a);
    float t = (1.0f - e) * __builtin_amdgcn_rcpf(1.0f + e);
    return copysignf(t, x);
}

__device__ __forceinline__ float b2f(short s) {
    return __uint_as_float(((unsigned)(unsigned short)s) << 16);
}

__device__ __forceinline__ bf16x8_t cvt8(const float4 f0, const float4 f1) {
    union { bf16x8_t s8; __hip_bfloat162 h[4]; } u;
    u.h[0] = __float22bfloat162_rn(make_float2(f0.x, f0.y));
    u.h[1] = __float22bfloat162_rn(make_float2(f0.z, f0.w));
    u.h[2] = __float22bfloat162_rn(make_float2(f1.x, f1.y));
    u.h[3] = __float22bfloat162_rn(make_float2(f1.z, f1.w));
    return u.s8;
}

__device__ __forceinline__ void gload16(const void* g, void* l) {
    __builtin_amdgcn_global_load_lds(
        (const __attribute__((address_space(1))) void*)g,
        (__attribute__((address_space(3))) void*)l, 16, 0, 0);
}

// kfused0: [0,1024) W[:, :1024] -> bf16 Wb (coalesced);
//          [1024,2048) dec_proj: one h/block, W_dec row staged in LDS,
//          32 b-dots with 8-lane chunk reduce (coalesced);
//          [2048,2560) enc -> bf16 encb, active 128-row tiles only.
// All three parts independent; consumers launch after this kernel.
__global__ __launch_bounds__(256) void kfused0(
    const float* __restrict__ W, const float* __restrict__ dec,
    const float* __restrict__ enc, const int* __restrict__ seq,
    __hip_bfloat16* __restrict__ Wb, float* __restrict__ dec_proj,
    __hip_bfloat16* __restrict__ encb)
{
    int blk = blockIdx.x, tid = threadIdx.x;
    if (blk < 1024) {
        int idx = (blk * 256 + tid) * 4;   // over H*E
        int h = idx >> 10, e = idx & 1023;
        float4 f = *(const float4*)(W + (size_t)h * 2048 + e);
        __hip_bfloat162 p0 = __float22bfloat162_rn(make_float2(f.x, f.y));
        __hip_bfloat162 p1 = __float22bfloat162_rn(make_float2(f.z, f.w));
        *reinterpret_cast<__hip_bfloat162*>(Wb + idx)     = p0;
        *reinterpret_cast<__hip_bfloat162*>(Wb + idx + 2) = p1;
    } else if (blk < 2048) {
        int h = blk - 1024;                 // 0..1023
        __shared__ float4 wlds[256];
        wlds[tid] = *(const float4*)(W + (size_t)h * 2048 + 1024 + tid * 4);
        __syncthreads();
        int b = tid >> 3, chunk = tid & 7;  // 32 b x 8 chunks of 128 elems
        const float4* dd = (const float4*)(dec + b * 1024 + chunk * 128);
        float acc = 0.f;
        #pragma unroll
        for (int i = 0; i < 32; ++i) {
            float4 w4 = wlds[chunk * 32 + i];
            float4 d4 = dd[i];
            acc += w4.x * d4.x + w4.y * d4.y + w4.z * d4.z + w4.w * d4.w;
        }
        acc += __shfl_xor(acc, 1);
        acc += __shfl_xor(acc, 2);
        acc += __shfl_xor(acc, 4);
        if (chunk == 0) dec_proj[b * H + h] = acc;
    } else {
        int g = blk - 2048;                 // 512: 16 s-chunks x 32 b
        int c = g & 15, b = g >> 4;
        if (c * 128 >= seq[b]) return;
        size_t base = ((size_t)b * S + c * 128) << 10;
        const float* src = enc + base;
        __hip_bfloat16* dst = encb + base;
        #pragma unroll 4
        for (int it = 0; it < 64; ++it) {
            int idx = it * 2048 + tid * 8;
            float4 f0 = *(const float4*)(src + idx);
            float4 f1 = *(const float4*)(src + idx + 4);
            *(bf16x8_t*)(dst + idx) = cvt8(f0, f1);
        }
    }
}

// K2: 128(s) x 128(h) tile, BK=64, K=1024, 4 waves (2x2), 64x64/wave.
// Proven 2-phase double-buffer (round 4, 153 us): stage(next) issued BEFORE
// ds_read+MFMA(cur); single per-iter __syncthreads drains vmcnt after MFMAs.
// XOR-swizzle byte col ^= (row&7)<<4 (0 bank conflicts). LDS 64 KiB -> 2
// blocks/CU. MODE 0: A+B via global_load_lds (encb, Wb). MODE 2: fallback,
// A reg-staged from fp32 enc.
// Grid 4096: pair=(bid>>6)*8+(bid&7); ht=(bid>>3)&7 -> the 8 ht-blocks of
// one (b,st) are 8 apart -> same XCD -> A-tile L2 reuse.
template<int MODE>
__global__ __launch_bounds__(256, 2) void k2_mfma(
    const float* __restrict__ enc, const __hip_bfloat16* __restrict__ encb,
    const __hip_bfloat16* __restrict__ Wb, const float* __restrict__ v,
    const float* __restrict__ dec_proj, const int* __restrict__ seq,
    float* __restrict__ part)
{
    const int bid  = blockIdx.x;
    const int pair = (bid >> 6) * 8 + (bid & 7);   // 0..511 = 16 s-tiles x 32 b
    const int ht   = (bid >> 3) & 7;
    const int b    = pair >> 4;
    const int s0   = (pair & 15) * 128;
    if (s0 >= seq[b]) return;
    const int h0 = ht * 128;

    const int tid  = threadIdx.x;
    const int wave = tid >> 6;
    const int lane = tid & 63;
    const int wr = wave >> 1, wc = wave & 1;   // 2x2 wave grid
    const int cr = lane & 15, cg = lane >> 4;

    __shared__ __hip_bfloat16 Al[2][128 * 64];
    __shared__ __hip_bfloat16 Bl[2][128 * 64];

    const int colb  = (tid & 7) * 16;   // byte col within 128B LDS row
    const int rbase = tid >> 3;         // 0..31

    f32x4_t acc[4][4];
    #pragma unroll
    for (int m = 0; m < 4; ++m)
        #pragma unroll
        for (int n = 0; n < 4; ++n)
            acc[m][n] = (f32x4_t){0.f, 0.f, 0.f, 0.f};

    auto stage = [&](int buf, int kt) {
        #pragma unroll
        for (int i = 0; i < 4; ++i) {
            const int row   = i * 32 + rbase;
            const int scolb = colb ^ ((row & 7) << 4);
            const __hip_bfloat16* bg =
                Wb + (((size_t)(h0 + row)) << 10) + kt * 64 + (scolb >> 1);
            gload16(bg, (char*)&Bl[buf][0] + (i * 256 + tid) * 16);
            if (MODE == 0) {
                const __hip_bfloat16* ag =
                    encb + (((size_t)b * S + s0 + row) << 10) + kt * 64 + (scolb >> 1);
                gload16(ag, (char*)&Al[buf][0] + (i * 256 + tid) * 16);
            } else {
                const float* af =
                    enc + (((size_t)b * S + s0 + row) << 10) + kt * 64 + (tid & 7) * 8;
                bf16x8_t v8 = cvt8(*(const float4*)af, *(const float4*)(af + 4));
                *(bf16x8_t*)((char*)&Al[buf][0] + row * 128 + scolb) = v8;
            }
        }
    };

    stage(0, 0);
    __syncthreads();
    int cur = 0;
    for (int kt = 0; kt < 16; ++kt) {
        if (kt < 15) stage(cur ^ 1, kt + 1);   // flies under the MFMAs below
        bf16x8_t afr[2][4], bfr[2][4];
        #pragma unroll
        for (int ks = 0; ks < 2; ++ks) {
            #pragma unroll
            for (int m = 0; m < 4; ++m) {
                const int arow  = wr * 64 + m * 16 + cr;
                const int acolb = (ks * 64 + cg * 16) ^ ((arow & 7) << 4);
                afr[ks][m] = *(const bf16x8_t*)((const char*)&Al[cur][0] + arow * 128 + acolb);
                const int brow  = wc * 64 + m * 16 + cr;
                const int bcolb = (ks * 64 + cg * 16) ^ ((brow & 7) << 4);
                bfr[ks][m] = *(const bf16x8_t*)((const char*)&Bl[cur][0] + brow * 128 + bcolb);
            }
        }
        #pragma unroll
        for (int ks = 0; ks < 2; ++ks)
            #pragma unroll
            for (int m = 0; m < 4; ++m)
                #pragma unroll
                for (int n = 0; n < 4; ++n)
                    acc[m][n] = __builtin_amdgcn_mfma_f32_16x16x32_bf16(
                        afr[ks][m], bfr[ks][n], acc[m][n], 0, 0, 0);
        __syncthreads();   // drains vmcnt+lgkmcnt: next buf ready, cur consumed
        cur ^= 1;
    }

    // Epilogue: t = v*tanh(acc + dec_proj); reduce over n frags + 16 cr lanes.
    float vv[4], dp[4];
    #pragma unroll
    for (int n = 0; n < 4; ++n) {
        int h = h0 + wc * 64 + n * 16 + cr;
        vv[n] = v[h];
        dp[n] = dec_proj[b * H + h];
    }
    #pragma unroll
    for (int m = 0; m < 4; ++m) {
        #pragma unroll
        for (int j = 0; j < 4; ++j) {
            float t = 0.f;
            #pragma unroll
            for (int n = 0; n < 4; ++n)
                t += vv[n] * fast_tanh(acc[m][n][j] + dp[n]);
            t += __shfl_xor(t, 1);
            t += __shfl_xor(t, 2);
            t += __shfl_xor(t, 4);
            t += __shfl_xor(t, 8);
            if (cr == 0) {
                int srow = s0 + wr * 64 + m * 16 + cg * 4 + j;
                part[(size_t)(b * S + srow) * 16 + ht * 2 + wc] = t;
            }
        }
    }
}

// K3: sum 16 partials -> logit; masked softmax over s per batch
__global__ __launch_bounds__(256) void k3_softmax(
    const float* __restrict__ part, const int* __restrict__ seq,
    float* __restrict__ attn)
{
    int b = blockIdx.x, tid = threadIdx.x;
    int len = seq[b];
    float vals[8];
    float mx = -3.4e38f;
    #pragma unroll
    for (int i = 0; i < 8; ++i) {
        int s = i * 256 + tid;
        float x = MASK_VAL;
        if (s < len) {
            const f32x4_t* p = (const f32x4_t*)&part[(size_t)(b * S + s) * 16];
            f32x4_t a = p[0], c = p[1], d = p[2], e = p[3];
            x = (a[0] + a[1] + a[2] + a[3]) + (c[0] + c[1] + c[2] + c[3]) +
                (d[0] + d[1] + d[2] + d[3]) + (e[0] + e[1] + e[2] + e[3]);
        }
        vals[i] = x;
        mx = fmaxf(mx, x);
    }
    #pragma unroll
    for (int off = 1; off < 64; off <<= 1) mx = fmaxf(mx, __shfl_xor(mx, off));
    __shared__ float red[8];
    int wave = tid >> 6, lane = tid & 63;
    if (lane == 0) red[wave] = mx;
    __syncthreads();
    mx = fmaxf(fmaxf(red[0], red[1]), fmaxf(red[2], red[3]));
    float e[8];
    float sum = 0.f;
    #pragma unroll
    for (int i = 0; i < 8; ++i) { e[i] = __expf(vals[i] - mx); sum += e[i]; }
    #pragma unroll
    for (int off = 1; off < 64; off <<= 1) sum += __shfl_xor(sum, off);
    if (lane == 0) red[4 + wave] = sum;
    __syncthreads();
    sum = red[4] + red[5] + red[6] + red[7];
    float inv = 1.0f / sum;
    #pragma unroll
    for (int i = 0; i < 8; ++i) attn[b * S + i * 256 + tid] = e[i] * inv;
}

// K4: opart partial weighted sums over 16 s-chunks of 128, 2-way s-split.
// AMODE 0: bf16 encb; AMODE 1: fp32 enc (fallback).
template<int AMODE>
__global__ __launch_bounds__(256) void k4_partial(
    const float* __restrict__ enc, const __hip_bfloat16* __restrict__ encb,
    const float* __restrict__ attn, const int* __restrict__ seq,
    float* __restrict__ opart)
{
    int c = blockIdx.x, b = blockIdx.y, tid = threadIdx.x;
    int base_s = c * 128;
    int len = seq[b];
    if (AMODE == 0) {
        int e0 = (tid & 127) * 8;
        int so = tid >> 7;
        float av[8];
        #pragma unroll
        for (int j = 0; j < 8; ++j) av[j] = 0.f;
        if (base_s < len) {
            int s_end = min(128, len - base_s);
            for (int s = so; s < s_end; s += 2) {
                float w = attn[b * S + base_s + s];
                bf16x8_t u = *(const bf16x8_t*)(encb +
                    (((size_t)b * S + base_s + s) << 10) + e0);
                #pragma unroll
                for (int j = 0; j < 8; ++j) av[j] += w * b2f(u[j]);
            }
        }
        float* dst = opart + (((size_t)(b * 16 + c) * 2 + so) << 10) + e0;
        *(float4*)dst       = make_float4(av[0], av[1], av[2], av[3]);
        *(float4*)(dst + 4) = make_float4(av[4], av[5], av[6], av[7]);
    } else {
        float4 acc = make_float4(0.f, 0.f, 0.f, 0.f);
        if (base_s < len) {
            int s_end = min(128, len - base_s);
            const float* ep = enc + (((size_t)b * S + base_s) << 10) + tid * 4;
            const float* ap = attn + b * S + base_s;
            for (int s = 0; s < s_end; ++s) {
                float w = ap[s];
                float4 ev = *(const float4*)ep;
                ep += E;
                acc.x += w * ev.x; acc.y += w * ev.y;
                acc.z += w * ev.z; acc.w += w * ev.w;
            }
        }
        float* dst = opart + (((size_t)(b * 16 + c) * 2) << 10) + tid * 4;
        *(float4*)dst = acc;
        float* dst2 = opart + (((size_t)(b * 16 + c) * 2 + 1) << 10) + tid * 4;
        *(float4*)dst2 = make_float4(0.f, 0.f, 0.f, 0.f);
    }
}

// K5: out[b][e] = sum over 32 partials
__global__ __launch_bounds__(256) void k5_reduce(
    const float* __restrict__ opart, float* __restrict__ out)
{
    int gid = blockIdx.x * 256 + threadIdx.x;  // 32768 = B*E
    int b = gid >> 10, e = gid & 1023;
    float s = 0.f;
    #pragma unroll
    for (int c = 0; c < 32; ++c) s += opart[((size_t)(b * 32 + c) << 10) + e];
    out[gid] = s;
}

extern "C" void kernel_launch(void* const* d_in, const int* in_sizes, int n_in,
                              void* d_out, int out_size, void* d_ws, size_t ws_size,
                              hipStream_t stream)
{
    const float* enc = (const float*)d_in[0];
    const int*   seq = (const int*)d_in[1];
    const float* dec = (const float*)d_in[2];
    const float* W   = (const float*)d_in[3];
    const float* v   = (const float*)d_in[4];

    float* out  = (float*)d_out;            // (B, E)
    float* attn = out + B * E;              // (B, S)

    float* dec_proj = (float*)d_ws;                         // B*H
    float* part     = dec_proj + B * H;                     // B*S*16
    float* opart    = part + (size_t)B * S * 16;            // B*32*1024
    __hip_bfloat16* Wb = (__hip_bfloat16*)(opart + (size_t)B * 32 * 1024);
    __hip_bfloat16* encb = Wb + (size_t)H * E;              // B*S*E bf16

    const size_t need = (size_t)(B * H + B * S * 16 + B * 32 * 1024) * 4
                      + (size_t)H * E * 2 + (size_t)B * S * E * 2;
    const bool use_encb = ws_size >= need;

    if (use_encb) {
        hipLaunchKernelGGL(kfused0, dim3(2560), dim3(256), 0, stream,
                           W, dec, enc, seq, Wb, dec_proj, encb);
        hipLaunchKernelGGL(k2_mfma<0>, dim3(4096), dim3(256), 0, stream,
                           enc, encb, Wb, v, dec_proj, seq, part);
    } else {
        hipLaunchKernelGGL(kfused0, dim3(2048), dim3(256), 0, stream,
                           W, dec, enc, seq, Wb, dec_proj, encb);
        hipLaunchKernelGGL(k2_mfma<2>, dim3(4096), dim3(256), 0, stream,
                           enc, encb, Wb, v, dec_proj, seq, part);
    }
    hipLaunchKernelGGL(k3_softmax, dim3(B), dim3(256), 0, stream,
                       part, seq, attn);
    if (use_encb) {
        hipLaunchKernelGGL(k4_partial<0>, dim3(16, B), dim3(256), 0, stream,
                           enc, encb, attn, seq, opart);
    } else {
        hipLaunchKernelGGL(k4_partial<1>, dim3(16, B), dim3(256), 0, stream,
                           enc, encb, attn, seq, opart);
    }
    hipLaunchKernelGGL(k5_reduce, dim3(B * E / 256), dim3(256), 0, stream,
                       opart, out);
}